// Round 2
// baseline (263.653 us; speedup 1.0000x reference)
//
#include <hip/hip_runtime.h>

// HRPLoss: B=64, K=17, H=96, W=72.
// d_in order: out1_1(B,K,H,W) out1_2(B,2K,H,W) out2_1(B,K,H,W) out2_2(B,2K,H,W)
//             targets1(B,K,H,W) targets2(B,2K,H,W) weights(2)
// All fp32. Output: single fp32 scalar.

constexpr int K    = 17;
constexpr int B    = 64;
constexpr int HW   = 96 * 72;      // 6912 (divisible by 4)
constexpr int NCH  = B * K;        // 1088 channels
constexpr int NF4  = HW / 4;       // 1728 float4 per channel
constexpr float INV_N = 1.0f / (float)(B * K * HW);  // 1/7,520,256

// ws layout (floats): [0,NCH) s21  [NCH,2N) p11  [2N,3N) p12  [3N,4N) p22
// total 4*1088*4 B = 17.4 KB

__global__ __launch_bounds__(256, 4) void fused_main(
    const float* __restrict__ o11, const float* __restrict__ o12,
    const float* __restrict__ o21, const float* __restrict__ o22,
    const float* __restrict__ t1,  const float* __restrict__ t2,
    float* __restrict__ ws)
{
    const int bk = blockIdx.x;           // channel id 0..1087
    const int b  = bk / K;
    const int k  = bk % K;
    const size_t base1  = (size_t)bk * HW;                     // (B,K,H,W) arrays
    const size_t base2x = ((size_t)(b * 2 * K + k)) * HW;      // (B,2K,H,W) x-part
    const size_t base2y = base2x + (size_t)K * HW;             // y-part

    const float4* po11  = (const float4*)(o11 + base1);
    const float4* po21  = (const float4*)(o21 + base1);
    const float4* pt1   = (const float4*)(t1  + base1);
    const float4* po12x = (const float4*)(o12 + base2x);
    const float4* po12y = (const float4*)(o12 + base2y);
    const float4* po22x = (const float4*)(o22 + base2x);
    const float4* po22y = (const float4*)(o22 + base2y);
    const float4* pt2x  = (const float4*)(t2  + base2x);
    const float4* pt2y  = (const float4*)(t2  + base2y);

    float s11 = 0.f, s21 = 0.f, s12 = 0.f, s22 = 0.f;

    for (int i = threadIdx.x; i < NF4; i += 256) {
        float4 a  = po11[i];
        float4 c  = po21[i];
        float4 t  = pt1[i];
        float4 x  = po12x[i];
        float4 y  = po12y[i];
        float4 u  = po22x[i];
        float4 v  = po22y[i];
        float4 tx = pt2x[i];
        float4 ty = pt2y[i];

        const float* af  = (const float*)&a;
        const float* cf  = (const float*)&c;
        const float* tf  = (const float*)&t;
        const float* xf  = (const float*)&x;
        const float* yf  = (const float*)&y;
        const float* uf  = (const float*)&u;
        const float* vf  = (const float*)&v;
        const float* txf = (const float*)&tx;
        const float* tyf = (const float*)&ty;

        #pragma unroll
        for (int j = 0; j < 4; ++j) {
            float tj = tf[j];
            float d;
            d = af[j] - tj;            s11 += d * d;   // loss1_1
            d = cf[j] - tj;            s21 += d * d;   // channel sum for topk / loss2_1
            d = xf[j] * tj - txf[j];   s12 += d * d;   // loss1_2 x
            d = yf[j] * tj - tyf[j];   s12 += d * d;   // loss1_2 y
            // loss2_2 (unmasked; mask applied in finalize): m = t1 for kept channels
            d = uf[j] * tj - txf[j] * tj;  s22 += d * d;
            d = vf[j] * tj - tyf[j] * tj;  s22 += d * d;
        }
    }

    // wave64 reduce then cross-wave via LDS (block = 4 waves)
    #pragma unroll
    for (int off = 32; off > 0; off >>= 1) {
        s11 += __shfl_down(s11, off, 64);
        s21 += __shfl_down(s21, off, 64);
        s12 += __shfl_down(s12, off, 64);
        s22 += __shfl_down(s22, off, 64);
    }
    __shared__ float sh[4][4];
    const int lane = threadIdx.x & 63;
    const int wv   = threadIdx.x >> 6;
    if (lane == 0) { sh[0][wv] = s11; sh[1][wv] = s21; sh[2][wv] = s12; sh[3][wv] = s22; }
    __syncthreads();
    if (threadIdx.x == 0) {
        ws[bk]            = sh[1][0] + sh[1][1] + sh[1][2] + sh[1][3];  // s21
        ws[NCH + bk]      = sh[0][0] + sh[0][1] + sh[0][2] + sh[0][3];  // p11
        ws[2 * NCH + bk]  = sh[2][0] + sh[2][1] + sh[2][2] + sh[2][3];  // p12
        ws[3 * NCH + bk]  = sh[3][0] + sh[3][1] + sh[3][2] + sh[3][3];  // p22
    }
}

__global__ __launch_bounds__(256) void finalize(
    const float* __restrict__ ws, const float* __restrict__ w,
    float* __restrict__ out)
{
    const float* ws21 = ws;
    const float* wp11 = ws + NCH;
    const float* wp12 = ws + 2 * NCH;
    const float* wp22 = ws + 3 * NCH;

    float p11 = 0.f, p12 = 0.f;
    for (int i = threadIdx.x; i < NCH; i += 256) {
        p11 += wp11[i];
        p12 += wp12[i];
    }

    float l21 = 0.f, s22m = 0.f;
    if (threadIdx.x < B) {
        const int b = threadIdx.x;
        float v[K];
        #pragma unroll
        for (int kk = 0; kk < K; ++kk) v[kk] = ws21[b * K + kk];
        unsigned sel = 0;
        for (int r = 0; r < K / 2; ++r) {        // top-8 of 17
            float bv = -3.402823466e+38f;
            int bi = 0;
            #pragma unroll
            for (int kk = 0; kk < K; ++kk) {
                bool taken = (sel >> kk) & 1u;
                if (!taken && v[kk] > bv) { bv = v[kk]; bi = kk; }  // strict >: ties pick lowest idx, matches top_k
            }
            sel |= 1u << bi;
            l21 += bv;
        }
        #pragma unroll
        for (int kk = 0; kk < K; ++kk)
            if ((sel >> kk) & 1u) s22m += wp22[b * K + kk];
    }

    // block reduce the 4 scalars
    #pragma unroll
    for (int off = 32; off > 0; off >>= 1) {
        p11  += __shfl_down(p11,  off, 64);
        p12  += __shfl_down(p12,  off, 64);
        l21  += __shfl_down(l21,  off, 64);
        s22m += __shfl_down(s22m, off, 64);
    }
    __shared__ float sh[4][4];
    const int lane = threadIdx.x & 63;
    const int wv   = threadIdx.x >> 6;
    if (lane == 0) { sh[0][wv] = p11; sh[1][wv] = p12; sh[2][wv] = l21; sh[3][wv] = s22m; }
    __syncthreads();
    if (threadIdx.x == 0) {
        float P11 = sh[0][0] + sh[0][1] + sh[0][2] + sh[0][3];
        float P12 = sh[1][0] + sh[1][1] + sh[1][2] + sh[1][3];
        float L21 = sh[2][0] + sh[2][1] + sh[2][2] + sh[2][3];
        float S22 = sh[3][0] + sh[3][1] + sh[3][2] + sh[3][3];

        float loss1_1 = P11 * INV_N;
        float loss1_2 = P12 * INV_N;
        float loss2_1 = L21 / (2.0f * B) / (float)(B * K);   // /(2B) then mean over B*K
        float loss2_2 = S22 * INV_N;

        out[0] = (loss1_1 + loss2_1) * w[0] + (loss1_2 + 5.0f * loss2_2) * w[1];
    }
}

extern "C" void kernel_launch(void* const* d_in, const int* in_sizes, int n_in,
                              void* d_out, int out_size, void* d_ws, size_t ws_size,
                              hipStream_t stream)
{
    const float* o11 = (const float*)d_in[0];
    const float* o12 = (const float*)d_in[1];
    const float* o21 = (const float*)d_in[2];
    const float* o22 = (const float*)d_in[3];
    const float* t1  = (const float*)d_in[4];
    const float* t2  = (const float*)d_in[5];
    const float* w   = (const float*)d_in[6];
    float* ws        = (float*)d_ws;

    hipLaunchKernelGGL(fused_main, dim3(NCH), dim3(256), 0, stream,
                       o11, o12, o21, o22, t1, t2, ws);
    hipLaunchKernelGGL(finalize, dim3(1), dim3(256), 0, stream,
                       ws, w, (float*)d_out);
}

// Round 7
// 260.317 us; speedup vs baseline: 1.0128x; 1.0128x over previous
//
#include <hip/hip_runtime.h>

// HRPLoss: B=64, K=17, H=96, W=72.
// d_in order: out1_1(B,K,H,W) out1_2(B,2K,H,W) out2_1(B,K,H,W) out2_2(B,2K,H,W)
//             targets1(B,K,H,W) targets2(B,2K,H,W) weights(2)
// All fp32. Output: single fp32 scalar.
//
// R2 post-mortem: 102us invariant cold-vs-warm cache => latency-bound, not BW.
// Occupancy 33.6% (grid-limited: 1088 blocks = 4.25/CU). Fix: split each
// channel into NSEG=2 segments -> 2176 blocks -> 8 blocks/CU resident
// (32 waves/CU). VGPR kept <=64 (no unroll) to stay on the 8-waves/SIMD side
// of the m69 occupancy cliff.

constexpr int K    = 17;
constexpr int B    = 64;
constexpr int HW   = 96 * 72;      // 6912
constexpr int NCH  = B * K;        // 1088 channels
constexpr int NF4  = HW / 4;       // 1728 float4 per channel
constexpr int NSEG = 2;
constexpr int SEGF4 = NF4 / NSEG;  // 864 float4 per segment
constexpr float INV_N = 1.0f / (float)(B * K * HW);  // 1/7,520,256

// ws layout (floats), NT = NCH*NSEG = 2176 entries per array:
//   [0,NT)      s21 partials   [NT,2NT)  p11   [2NT,3NT) p12   [3NT,4NT) p22
constexpr int NT = NCH * NSEG;

__global__ __launch_bounds__(256) void fused_main(
    const float* __restrict__ o11, const float* __restrict__ o12,
    const float* __restrict__ o21, const float* __restrict__ o22,
    const float* __restrict__ t1,  const float* __restrict__ t2,
    float* __restrict__ ws)
{
    const int bk  = blockIdx.x >> 1;     // channel id 0..1087
    const int seg = blockIdx.x & 1;      // segment 0/1
    const int b   = bk / K;
    const int k   = bk % K;
    const size_t base1  = (size_t)bk * HW;                     // (B,K,H,W) arrays
    const size_t base2x = ((size_t)(b * 2 * K + k)) * HW;      // (B,2K,H,W) x-part
    const size_t base2y = base2x + (size_t)K * HW;             // y-part

    const float4* po11  = (const float4*)(o11 + base1);
    const float4* po21  = (const float4*)(o21 + base1);
    const float4* pt1   = (const float4*)(t1  + base1);
    const float4* po12x = (const float4*)(o12 + base2x);
    const float4* po12y = (const float4*)(o12 + base2y);
    const float4* po22x = (const float4*)(o22 + base2x);
    const float4* po22y = (const float4*)(o22 + base2y);
    const float4* pt2x  = (const float4*)(t2  + base2x);
    const float4* pt2y  = (const float4*)(t2  + base2y);

    float s11 = 0.f, s21 = 0.f, s12 = 0.f, s22 = 0.f;

    const int iEnd = (seg + 1) * SEGF4;
    for (int i = seg * SEGF4 + threadIdx.x; i < iEnd; i += 256) {
        float4 a  = po11[i];
        float4 c  = po21[i];
        float4 t  = pt1[i];
        float4 x  = po12x[i];
        float4 y  = po12y[i];
        float4 u  = po22x[i];
        float4 v  = po22y[i];
        float4 tx = pt2x[i];
        float4 ty = pt2y[i];

        const float* af  = (const float*)&a;
        const float* cf  = (const float*)&c;
        const float* tf  = (const float*)&t;
        const float* xf  = (const float*)&x;
        const float* yf  = (const float*)&y;
        const float* uf  = (const float*)&u;
        const float* vf  = (const float*)&v;
        const float* txf = (const float*)&tx;
        const float* tyf = (const float*)&ty;

        #pragma unroll
        for (int j = 0; j < 4; ++j) {
            float tj = tf[j];
            float d;
            d = af[j] - tj;            s11 += d * d;   // loss1_1
            d = cf[j] - tj;            s21 += d * d;   // channel sum for topk / loss2_1
            d = xf[j] * tj - txf[j];   s12 += d * d;   // loss1_2 x
            d = yf[j] * tj - tyf[j];   s12 += d * d;   // loss1_2 y
            d = uf[j] * tj - txf[j] * tj;  s22 += d * d;  // loss2_2 x (mask in finalize)
            d = vf[j] * tj - tyf[j] * tj;  s22 += d * d;  // loss2_2 y
        }
    }

    // wave64 reduce then cross-wave via LDS (block = 4 waves)
    #pragma unroll
    for (int off = 32; off > 0; off >>= 1) {
        s11 += __shfl_down(s11, off, 64);
        s21 += __shfl_down(s21, off, 64);
        s12 += __shfl_down(s12, off, 64);
        s22 += __shfl_down(s22, off, 64);
    }
    __shared__ float sh[4][4];
    const int lane = threadIdx.x & 63;
    const int wv   = threadIdx.x >> 6;
    if (lane == 0) { sh[0][wv] = s11; sh[1][wv] = s21; sh[2][wv] = s12; sh[3][wv] = s22; }
    __syncthreads();
    if (threadIdx.x == 0) {
        const int slot = bk * NSEG + seg;
        ws[slot]          = sh[1][0] + sh[1][1] + sh[1][2] + sh[1][3];  // s21
        ws[NT + slot]     = sh[0][0] + sh[0][1] + sh[0][2] + sh[0][3];  // p11
        ws[2 * NT + slot] = sh[2][0] + sh[2][1] + sh[2][2] + sh[2][3];  // p12
        ws[3 * NT + slot] = sh[3][0] + sh[3][1] + sh[3][2] + sh[3][3];  // p22
    }
}

__global__ __launch_bounds__(256) void finalize(
    const float* __restrict__ ws, const float* __restrict__ w,
    float* __restrict__ out)
{
    const float* ws21 = ws;
    const float* wp11 = ws + NT;
    const float* wp12 = ws + 2 * NT;
    const float* wp22 = ws + 3 * NT;

    float p11 = 0.f, p12 = 0.f;
    for (int i = threadIdx.x; i < NT; i += 256) {
        p11 += wp11[i];
        p12 += wp12[i];
    }

    float l21 = 0.f, s22m = 0.f;
    if (threadIdx.x < B) {
        const int b = threadIdx.x;
        float v[K];
        #pragma unroll
        for (int kk = 0; kk < K; ++kk)
            v[kk] = ws21[(b * K + kk) * NSEG] + ws21[(b * K + kk) * NSEG + 1];
        unsigned sel = 0;
        for (int r = 0; r < K / 2; ++r) {        // top-8 of 17
            float bv = -3.402823466e+38f;
            int bi = 0;
            #pragma unroll
            for (int kk = 0; kk < K; ++kk) {
                bool taken = (sel >> kk) & 1u;
                if (!taken && v[kk] > bv) { bv = v[kk]; bi = kk; }  // strict >: ties -> lowest idx, matches top_k
            }
            sel |= 1u << bi;
            l21 += bv;
        }
        #pragma unroll
        for (int kk = 0; kk < K; ++kk)
            if ((sel >> kk) & 1u)
                s22m += wp22[(b * K + kk) * NSEG] + wp22[(b * K + kk) * NSEG + 1];
    }

    // block reduce the 4 scalars
    #pragma unroll
    for (int off = 32; off > 0; off >>= 1) {
        p11  += __shfl_down(p11,  off, 64);
        p12  += __shfl_down(p12,  off, 64);
        l21  += __shfl_down(l21,  off, 64);
        s22m += __shfl_down(s22m, off, 64);
    }
    __shared__ float sh[4][4];
    const int lane = threadIdx.x & 63;
    const int wv   = threadIdx.x >> 6;
    if (lane == 0) { sh[0][wv] = p11; sh[1][wv] = p12; sh[2][wv] = l21; sh[3][wv] = s22m; }
    __syncthreads();
    if (threadIdx.x == 0) {
        float P11 = sh[0][0] + sh[0][1] + sh[0][2] + sh[0][3];
        float P12 = sh[1][0] + sh[1][1] + sh[1][2] + sh[1][3];
        float L21 = sh[2][0] + sh[2][1] + sh[2][2] + sh[2][3];
        float S22 = sh[3][0] + sh[3][1] + sh[3][2] + sh[3][3];

        float loss1_1 = P11 * INV_N;
        float loss1_2 = P12 * INV_N;
        float loss2_1 = L21 / (2.0f * B) / (float)(B * K);   // /(2B) then mean over B*K
        float loss2_2 = S22 * INV_N;

        out[0] = (loss1_1 + loss2_1) * w[0] + (loss1_2 + 5.0f * loss2_2) * w[1];
    }
}

extern "C" void kernel_launch(void* const* d_in, const int* in_sizes, int n_in,
                              void* d_out, int out_size, void* d_ws, size_t ws_size,
                              hipStream_t stream)
{
    const float* o11 = (const float*)d_in[0];
    const float* o12 = (const float*)d_in[1];
    const float* o21 = (const float*)d_in[2];
    const float* o22 = (const float*)d_in[3];
    const float* t1  = (const float*)d_in[4];
    const float* t2  = (const float*)d_in[5];
    const float* w   = (const float*)d_in[6];
    float* ws        = (float*)d_ws;

    hipLaunchKernelGGL(fused_main, dim3(NCH * NSEG), dim3(256), 0, stream,
                       o11, o12, o21, o22, t1, t2, ws);
    hipLaunchKernelGGL(finalize, dim3(1), dim3(256), 0, stream,
                       ws, w, (float*)d_out);
}

// Round 8
// 232.803 us; speedup vs baseline: 1.1325x; 1.1182x over previous
//
#include <hip/hip_runtime.h>

// HRPLoss: B=64, K=17, H=96, W=72. All fp32, output = 1 scalar.
// d_in: out1_1(B,K,H,W) out1_2(B,2K,H,W) out2_1(B,K,H,W) out2_2(B,2K,H,W)
//       targets1(B,K,H,W) targets2(B,2K,H,W) weights(2)
//
// R7 post-mortem: occupancy 33->59% with dur FLAT at 100us => wave count was
// not the constraint. VGPR_Count=32 proves the compiler serialized the 9
// float4 loads (36 dest VGPRs don't fit) -> ~1 outstanding request/wave ->
// ingress capped at 4.4 B/cyc/CU. This round: straight-line ONE-SHOT blocks.
// Each thread loads exactly one float4 from each of the 9 streams (all
// results simultaneously live -> compiler must batch: 9 back-to-back
// global_load_dwordx4, ~50-60 VGPR). NSEG=9, block=192 (3 waves),
// grid=9792. Loads nontemporal (zero reuse). Reduction: main -> seg-reduce
// (mid) -> final.

typedef float f32x4 __attribute__((ext_vector_type(4)));

constexpr int K     = 17;
constexpr int B     = 64;
constexpr int HW    = 96 * 72;        // 6912
constexpr int NCH   = B * K;          // 1088 channels
constexpr int NF4   = HW / 4;         // 1728 float4 per channel
constexpr int NSEG  = 9;
constexpr int SEGW  = NF4 / NSEG;     // 192 float4 per segment == block size
constexpr int NT9   = NCH * NSEG;     // 9792 partial slots
constexpr int WS2   = 4 * NT9;        // float offset of compact region
constexpr float INV_N = 1.0f / (float)(B * K * HW);

// ws layout (floats):
//   [0       , NT9)   s21 per-(ch,seg)
//   [NT9     , 2*NT9) p11
//   [2*NT9   , 3*NT9) p12
//   [3*NT9   , 4*NT9) p22
//   [WS2     , WS2+4*NCH) compact per-channel: s21 | p11 | p12 | p22
// total (4*9792 + 4*1088)*4B = 174 KB

__global__ __launch_bounds__(192) void fused_main(
    const float* __restrict__ o11, const float* __restrict__ o12,
    const float* __restrict__ o21, const float* __restrict__ o22,
    const float* __restrict__ t1,  const float* __restrict__ t2,
    float* __restrict__ ws)
{
    const int bk  = blockIdx.x / NSEG;          // channel 0..1087
    const int seg = blockIdx.x - bk * NSEG;     // segment 0..8
    const int b   = bk / K;
    const int k   = bk - b * K;
    const int i   = seg * SEGW + threadIdx.x;   // float4 index in channel

    const size_t base1  = (size_t)bk * HW;                  // (B,K,H,W)
    const size_t base2x = ((size_t)(b * 2 * K + k)) * HW;   // (B,2K,H,W) x
    const size_t base2y = base2x + (size_t)K * HW;          // y

    // 9 independent nontemporal float4 loads — all live at once (forces batch)
    f32x4 a  = __builtin_nontemporal_load((const f32x4*)(o11 + base1)  + i);
    f32x4 c  = __builtin_nontemporal_load((const f32x4*)(o21 + base1)  + i);
    f32x4 t  = __builtin_nontemporal_load((const f32x4*)(t1  + base1)  + i);
    f32x4 x  = __builtin_nontemporal_load((const f32x4*)(o12 + base2x) + i);
    f32x4 y  = __builtin_nontemporal_load((const f32x4*)(o12 + base2y) + i);
    f32x4 u  = __builtin_nontemporal_load((const f32x4*)(o22 + base2x) + i);
    f32x4 v  = __builtin_nontemporal_load((const f32x4*)(o22 + base2y) + i);
    f32x4 tx = __builtin_nontemporal_load((const f32x4*)(t2  + base2x) + i);
    f32x4 ty = __builtin_nontemporal_load((const f32x4*)(t2  + base2y) + i);

    float s11 = 0.f, s21 = 0.f, s12 = 0.f, s22 = 0.f;
    #pragma unroll
    for (int j = 0; j < 4; ++j) {
        const float tj = t[j];
        float d;
        d = a[j] - tj;                 s11 += d * d;   // loss1_1
        d = c[j] - tj;                 s21 += d * d;   // topk channel sum
        d = x[j] * tj - tx[j];         s12 += d * d;   // loss1_2 x
        d = y[j] * tj - ty[j];         s12 += d * d;   // loss1_2 y
        d = (u[j] - tx[j]) * tj;       s22 += d * d;   // loss2_2 x (mask later)
        d = (v[j] - ty[j]) * tj;       s22 += d * d;   // loss2_2 y
    }

    // block reduce: 3 waves
    #pragma unroll
    for (int off = 32; off > 0; off >>= 1) {
        s11 += __shfl_down(s11, off, 64);
        s21 += __shfl_down(s21, off, 64);
        s12 += __shfl_down(s12, off, 64);
        s22 += __shfl_down(s22, off, 64);
    }
    __shared__ float sh[4][3];
    const int lane = threadIdx.x & 63;
    const int wv   = threadIdx.x >> 6;
    if (lane == 0) { sh[0][wv] = s11; sh[1][wv] = s21; sh[2][wv] = s12; sh[3][wv] = s22; }
    __syncthreads();
    if (threadIdx.x == 0) {
        const int slot = bk * NSEG + seg;
        ws[slot]           = sh[1][0] + sh[1][1] + sh[1][2];  // s21
        ws[NT9 + slot]     = sh[0][0] + sh[0][1] + sh[0][2];  // p11
        ws[2 * NT9 + slot] = sh[2][0] + sh[2][1] + sh[2][2];  // p12
        ws[3 * NT9 + slot] = sh[3][0] + sh[3][1] + sh[3][2];  // p22
    }
}

// seg-reduce: one thread per channel sums its 9 segment partials (deterministic order)
__global__ __launch_bounds__(256) void mid_reduce(float* __restrict__ ws)
{
    const int ch = blockIdx.x * 256 + threadIdx.x;
    if (ch >= NCH) return;
    float s0 = 0.f, s1 = 0.f, s2 = 0.f, s3 = 0.f;
    #pragma unroll
    for (int s = 0; s < NSEG; ++s) {
        const int slot = ch * NSEG + s;
        s0 += ws[slot];
        s1 += ws[NT9 + slot];
        s2 += ws[2 * NT9 + slot];
        s3 += ws[3 * NT9 + slot];
    }
    ws[WS2 + ch]           = s0;  // s21
    ws[WS2 + NCH + ch]     = s1;  // p11
    ws[WS2 + 2 * NCH + ch] = s2;  // p12
    ws[WS2 + 3 * NCH + ch] = s3;  // p22
}

__global__ __launch_bounds__(256) void finalize(
    const float* __restrict__ ws, const float* __restrict__ w,
    float* __restrict__ out)
{
    const float* c21  = ws + WS2;
    const float* cp11 = ws + WS2 + NCH;
    const float* cp12 = ws + WS2 + 2 * NCH;
    const float* cp22 = ws + WS2 + 3 * NCH;

    float p11 = 0.f, p12 = 0.f;
    for (int i = threadIdx.x; i < NCH; i += 256) {
        p11 += cp11[i];
        p12 += cp12[i];
    }

    float l21 = 0.f, s22m = 0.f;
    if (threadIdx.x < B) {
        const int b = threadIdx.x;
        float v[K];
        #pragma unroll
        for (int kk = 0; kk < K; ++kk) v[kk] = c21[b * K + kk];
        unsigned sel = 0;
        for (int r = 0; r < K / 2; ++r) {        // top-8 of 17
            float bv = -3.402823466e+38f;
            int bi = 0;
            #pragma unroll
            for (int kk = 0; kk < K; ++kk) {
                bool taken = (sel >> kk) & 1u;
                if (!taken && v[kk] > bv) { bv = v[kk]; bi = kk; }  // strict >: ties -> lowest idx = top_k
            }
            sel |= 1u << bi;
            l21 += bv;
        }
        #pragma unroll
        for (int kk = 0; kk < K; ++kk)
            if ((sel >> kk) & 1u) s22m += cp22[b * K + kk];
    }

    #pragma unroll
    for (int off = 32; off > 0; off >>= 1) {
        p11  += __shfl_down(p11,  off, 64);
        p12  += __shfl_down(p12,  off, 64);
        l21  += __shfl_down(l21,  off, 64);
        s22m += __shfl_down(s22m, off, 64);
    }
    __shared__ float sh[4][4];
    const int lane = threadIdx.x & 63;
    const int wv   = threadIdx.x >> 6;
    if (lane == 0) { sh[0][wv] = p11; sh[1][wv] = p12; sh[2][wv] = l21; sh[3][wv] = s22m; }
    __syncthreads();
    if (threadIdx.x == 0) {
        float P11 = sh[0][0] + sh[0][1] + sh[0][2] + sh[0][3];
        float P12 = sh[1][0] + sh[1][1] + sh[1][2] + sh[1][3];
        float L21 = sh[2][0] + sh[2][1] + sh[2][2] + sh[2][3];
        float S22 = sh[3][0] + sh[3][1] + sh[3][2] + sh[3][3];

        float loss1_1 = P11 * INV_N;
        float loss1_2 = P12 * INV_N;
        float loss2_1 = L21 / (2.0f * B) / (float)(B * K);
        float loss2_2 = S22 * INV_N;

        out[0] = (loss1_1 + loss2_1) * w[0] + (loss1_2 + 5.0f * loss2_2) * w[1];
    }
}

extern "C" void kernel_launch(void* const* d_in, const int* in_sizes, int n_in,
                              void* d_out, int out_size, void* d_ws, size_t ws_size,
                              hipStream_t stream)
{
    const float* o11 = (const float*)d_in[0];
    const float* o12 = (const float*)d_in[1];
    const float* o21 = (const float*)d_in[2];
    const float* o22 = (const float*)d_in[3];
    const float* t1  = (const float*)d_in[4];
    const float* t2  = (const float*)d_in[5];
    const float* w   = (const float*)d_in[6];
    float* ws        = (float*)d_ws;

    hipLaunchKernelGGL(fused_main, dim3(NCH * NSEG), dim3(192), 0, stream,
                       o11, o12, o21, o22, t1, t2, ws);
    hipLaunchKernelGGL(mid_reduce, dim3((NCH + 255) / 256), dim3(256), 0, stream, ws);
    hipLaunchKernelGGL(finalize, dim3(1), dim3(256), 0, stream,
                       ws, w, (float*)d_out);
}